// Round 2
// baseline (477.498 us; speedup 1.0000x reference)
//
#include <hip/hip_runtime.h>
#include <hip/hip_bf16.h>
#include <cstdint>
#include <cstddef>

// Problem constants
#define B_ 4
#define K_ 8192
#define D_ 1024
#define M_ (B_*K_)      // 32768 rows in the GEMM

// Scan chunking: 256 chunks of 32 timesteps
#define CCH 256
#define LCH (K_/CCH)    // 32

typedef __bf16 bf16x8 __attribute__((ext_vector_type(8)));
typedef float  f32x4  __attribute__((ext_vector_type(4)));

typedef __attribute__((address_space(1))) void as1void;
typedef __attribute__((address_space(3))) void as3void;

__device__ __forceinline__ void gload_lds16(const void* g, void* l) {
  // 16B-wide async global->LDS. LDS dest is wave-uniform base + lane*16.
  __builtin_amdgcn_global_load_lds((as1void*)g, (as3void*)l, 16, 0, 0);
}

__device__ __forceinline__ unsigned short f2bf_rne(float f) {
  unsigned u = __builtin_bit_cast(unsigned, f);
  u += 0x7fffu + ((u >> 16) & 1u);   // round-to-nearest-even
  return (unsigned short)(u >> 16);
}

// ---------------------------------------------------------------- convert ---
__global__ __launch_bounds__(256) void cvt_f32_to_bf16(
    const float* __restrict__ in, unsigned short* __restrict__ out, int n4) {
  int stride = gridDim.x * blockDim.x;
  for (int i = blockIdx.x * blockDim.x + threadIdx.x; i < n4; i += stride) {
    float4 v = reinterpret_cast<const float4*>(in)[i];
    ushort4 o;
    o.x = f2bf_rne(v.x); o.y = f2bf_rne(v.y);
    o.z = f2bf_rne(v.z); o.w = f2bf_rne(v.w);
    reinterpret_cast<ushort4*>(out)[i] = o;
  }
}

// ------------------------------------------------------------------- GEMM ---
// lam[m,e] = sigmoid( sum_d x[m,d]*W[e,d] + bias[e] )
// A = x_bf16 [M][1024] row-major, Bw = W_bf16 [1024][1024] row-major (NT GEMM).
// m97 structure: 128x128 block tile, 4 waves (2x2), BK=32, global_load_lds x16.
__global__ __launch_bounds__(256) void gemm_bias_sigmoid(
    const unsigned short* __restrict__ A,
    const unsigned short* __restrict__ Bw,
    const float* __restrict__ bias,
    float* __restrict__ lam) {
  __shared__ __attribute__((aligned(16))) unsigned short Alds[128 * 32];  // 8KB
  __shared__ __attribute__((aligned(16))) unsigned short Blds[128 * 32];  // 8KB

  const int t    = threadIdx.x;
  const int wave = t >> 6;
  const int lane = t & 63;
  const int wr   = wave >> 1;     // wave row (0..1), 64 rows each
  const int wc   = wave & 1;      // wave col (0..1), 64 cols each
  const int m0   = blockIdx.x * 128;
  const int n0   = blockIdx.y * 128;

  f32x4 acc[4][4] = {};   // 4x4 fragments of 16x16 per wave -> 64x64

  // Staging: linear16 slot q = issue*256 + t covers LDS bytes [q*16, q*16+16)
  // row = q/4, k-col = (q%4)*8  (row-major [128][32] bf16 tile = 64B rows)
  const int r0 = t >> 2;
  const int c0 = (t & 3) * 8;
  const unsigned short* gA0 = A  + (size_t)(m0 + r0)      * D_ + c0;
  const unsigned short* gA1 = A  + (size_t)(m0 + r0 + 64) * D_ + c0;
  const unsigned short* gB0 = Bw + (size_t)(n0 + r0)      * D_ + c0;
  const unsigned short* gB1 = Bw + (size_t)(n0 + r0 + 64) * D_ + c0;
  // wave-uniform LDS bases (8 shorts = 16B per slot)
  unsigned short* lA0 = Alds + (       wave * 64) * 8;
  unsigned short* lA1 = Alds + (256 +  wave * 64) * 8;
  unsigned short* lB0 = Blds + (       wave * 64) * 8;
  unsigned short* lB1 = Blds + (256 +  wave * 64) * 8;

  // fragment read offsets (elements):
  // A-frag lane l: row = wr*64 + m*16 + (l&15), k = (l>>4)*8 .. +8
  const int aoff = (wr * 64 + (lane & 15)) * 32 + ((lane >> 4) * 8);
  const int boff = (wc * 64 + (lane & 15)) * 32 + ((lane >> 4) * 8);

  for (int kt = 0; kt < D_; kt += 32) {
    gload_lds16(gA0 + kt, lA0);
    gload_lds16(gA1 + kt, lA1);
    gload_lds16(gB0 + kt, lB0);
    gload_lds16(gB1 + kt, lB1);
    __syncthreads();          // drains vmcnt before barrier -> LDS ready
    bf16x8 af[4], bf[4];
#pragma unroll
    for (int m = 0; m < 4; ++m)
      af[m] = *reinterpret_cast<const bf16x8*>(&Alds[aoff + m * 16 * 32]);
#pragma unroll
    for (int n = 0; n < 4; ++n)
      bf[n] = *reinterpret_cast<const bf16x8*>(&Blds[boff + n * 16 * 32]);
#pragma unroll
    for (int m = 0; m < 4; ++m)
#pragma unroll
      for (int n = 0; n < 4; ++n)
        acc[m][n] = __builtin_amdgcn_mfma_f32_16x16x32_bf16(af[m], bf[n], acc[m][n], 0, 0, 0);
    __syncthreads();          // before next-iteration staging overwrites LDS
  }

  // Epilogue: C/D layout col = lane&15, row = (lane>>4)*4 + r  [m89/m91]
  const int erow = m0 + wr * 64 + ((lane >> 4) << 2);
  const int ecol = n0 + wc * 64 + (lane & 15);
#pragma unroll
  for (int n = 0; n < 4; ++n) {
    const int col = ecol + n * 16;
    const float bv = bias[col];
#pragma unroll
    for (int m = 0; m < 4; ++m) {
#pragma unroll
      for (int r = 0; r < 4; ++r) {
        const int row = erow + m * 16 + r;
        const float z = acc[m][n][r] + bv;
        lam[(size_t)row * D_ + col] = 1.0f / (1.0f + __expf(-z));
      }
    }
  }
}

// ------------------------------------------------------------- scan pass 1 --
// Per (b, chunk c, 4 d-lanes): local scan with s=0; emit P = prod(lam),
// A = local scan end-state.
__global__ __launch_bounds__(256) void scan_pass1(
    const float* __restrict__ lam, const float* __restrict__ x,
    float* __restrict__ P, float* __restrict__ Aarr) {
  const int blk = blockIdx.x;
  const int b = blk / CCH, c = blk % CCH;
  const int d4 = threadIdx.x * 4;
  const size_t base = ((size_t)(b * K_ + c * LCH)) * D_ + d4;
  const float4* lp = reinterpret_cast<const float4*>(lam + base);
  const float4* xp = reinterpret_cast<const float4*>(x + base);
  float4 s = {0.f, 0.f, 0.f, 0.f};
  float4 p = {1.f, 1.f, 1.f, 1.f};
#pragma unroll 8
  for (int k = 0; k < LCH; ++k) {
    float4 l  = lp[k * (D_ / 4)];
    float4 xv = xp[k * (D_ / 4)];
    p.x *= l.x; p.y *= l.y; p.z *= l.z; p.w *= l.w;
    s.x = l.x * s.x + (1.f - l.x) * xv.x;
    s.y = l.y * s.y + (1.f - l.y) * xv.y;
    s.z = l.z * s.z + (1.f - l.z) * xv.z;
    s.w = l.w * s.w + (1.f - l.w) * xv.w;
  }
  const size_t o = ((size_t)(b * CCH + c)) * D_ + d4;
  *reinterpret_cast<float4*>(P + o)    = p;
  *reinterpret_cast<float4*>(Aarr + o) = s;
}

// ------------------------------------------------------------- scan pass 2 --
// Sequential over 256 chunks per (b,d) lane: S_c = incoming state of chunk c.
__global__ __launch_bounds__(256) void scan_pass2(
    const float* __restrict__ P, const float* __restrict__ Aarr,
    float* __restrict__ S) {
  const int g = blockIdx.x * 256 + threadIdx.x;  // 0..4095
  const int b = g >> 10;
  const int d = g & 1023;
  float s = 0.f;
  size_t o = (size_t)(b * CCH) * D_ + d;
  for (int c = 0; c < CCH; ++c, o += D_) {
    S[o] = s;
    s = Aarr[o] + P[o] * s;
  }
}

// ------------------------------------------------------------- scan pass 3 --
// Replay each chunk with correct incoming state, write outputs.
__global__ __launch_bounds__(256) void scan_pass3(
    const float* __restrict__ lam, const float* __restrict__ x,
    const float* __restrict__ S, float* __restrict__ out) {
  const int blk = blockIdx.x;
  const int b = blk / CCH, c = blk % CCH;
  const int d4 = threadIdx.x * 4;
  float4 s = *reinterpret_cast<const float4*>(S + ((size_t)(b * CCH + c)) * D_ + d4);
  const size_t base = ((size_t)(b * K_ + c * LCH)) * D_ + d4;
  const float4* lp = reinterpret_cast<const float4*>(lam + base);
  const float4* xp = reinterpret_cast<const float4*>(x + base);
  float4* op = reinterpret_cast<float4*>(out + base);
#pragma unroll 8
  for (int k = 0; k < LCH; ++k) {
    float4 l  = lp[k * (D_ / 4)];
    float4 xv = xp[k * (D_ / 4)];
    s.x = l.x * s.x + (1.f - l.x) * xv.x;
    s.y = l.y * s.y + (1.f - l.y) * xv.y;
    s.z = l.z * s.z + (1.f - l.z) * xv.z;
    s.w = l.w * s.w + (1.f - l.w) * xv.w;
    op[k * (D_ / 4)] = s;
  }
}

// ------------------------------------------------------------------ launch --
extern "C" void kernel_launch(void* const* d_in, const int* in_sizes, int n_in,
                              void* d_out, int out_size, void* d_ws, size_t ws_size,
                              hipStream_t stream) {
  const float* x    = (const float*)d_in[0];  // [B,K,D]
  const float* W    = (const float*)d_in[1];  // [D,D]
  const float* bias = (const float*)d_in[2];  // [D]
  float* out = (float*)d_out;

  // workspace carve-up (~206 MiB total)
  char* ws = (char*)d_ws;
  unsigned short* xbf = (unsigned short*)ws;                          // 64 MB
  unsigned short* wbf = (unsigned short*)(ws + (size_t)M_ * D_ * 2);  // 2 MB
  float* lam  = (float*)(ws + (size_t)M_ * D_ * 2 + (size_t)D_ * D_ * 2); // 128 MB
  float* P    = lam + (size_t)M_ * D_;          // 4 MB
  float* Aarr = P   + (size_t)B_ * CCH * D_;    // 4 MB
  float* S    = Aarr + (size_t)B_ * CCH * D_;   // 4 MB

  cvt_f32_to_bf16<<<2048, 256, 0, stream>>>(x, xbf, M_ * D_ / 4);
  cvt_f32_to_bf16<<<512, 256, 0, stream>>>(W, wbf, D_ * D_ / 4);
  gemm_bias_sigmoid<<<dim3(M_ / 128, D_ / 128), 256, 0, stream>>>(xbf, wbf, bias, lam);
  scan_pass1<<<B_ * CCH, 256, 0, stream>>>(lam, x, P, Aarr);
  scan_pass2<<<(B_ * D_) / 256, 256, 0, stream>>>(P, Aarr, S);  // 16 blocks
  scan_pass3<<<B_ * CCH, 256, 0, stream>>>(lam, x, S, out);
}

// Round 3
// 438.837 us; speedup vs baseline: 1.0881x; 1.0881x over previous
//
#include <hip/hip_runtime.h>
#include <hip/hip_bf16.h>
#include <hip/hip_fp16.h>
#include <cstdint>
#include <cstddef>

// Problem constants
#define B_ 4
#define K_ 8192
#define D_ 1024
#define M_ (B_*K_)      // 32768 rows in the GEMM
#define BD_ (B_*D_)     // 4096 scan chains

// Scan chunking: 256 chunks of 32 timesteps
#define CCH 256
#define LCH (K_/CCH)    // 32

typedef __bf16    bf16x8 __attribute__((ext_vector_type(8)));
typedef float     f32x4  __attribute__((ext_vector_type(4)));
typedef _Float16  f16x4  __attribute__((ext_vector_type(4)));

typedef __attribute__((address_space(1))) void as1void;
typedef __attribute__((address_space(3))) void as3void;

__device__ __forceinline__ void gload_lds16(const void* g, void* l) {
  // 16B-wide async global->LDS. LDS dest is wave-uniform base + lane*16.
  __builtin_amdgcn_global_load_lds((as1void*)g, (as3void*)l, 16, 0, 0);
}

__device__ __forceinline__ unsigned short f2bf_rne(float f) {
  unsigned u = __builtin_bit_cast(unsigned, f);
  u += 0x7fffu + ((u >> 16) & 1u);   // round-to-nearest-even
  return (unsigned short)(u >> 16);
}

// ---------------------------------------------------------------- convert ---
__global__ __launch_bounds__(256) void cvt_f32_to_bf16(
    const float* __restrict__ in, unsigned short* __restrict__ out, int n4) {
  int stride = gridDim.x * blockDim.x;
  for (int i = blockIdx.x * blockDim.x + threadIdx.x; i < n4; i += stride) {
    float4 v = reinterpret_cast<const float4*>(in)[i];
    ushort4 o;
    o.x = f2bf_rne(v.x); o.y = f2bf_rne(v.y);
    o.z = f2bf_rne(v.z); o.w = f2bf_rne(v.w);
    reinterpret_cast<ushort4*>(out)[i] = o;
  }
}

// ------------------------------------------------------------------- GEMM ---
// lam[m,e] = sigmoid( sum_d x[m,d]*W[e,d] + bias[e] ), stored as fp16.
// A = x_bf16 [M][1024] row-major, Bw = W_bf16 [1024][1024] row-major (NT GEMM).
// m97 structure: 128x128 block tile, 4 waves (2x2), BK=32, global_load_lds x16.
__global__ __launch_bounds__(256) void gemm_bias_sigmoid(
    const unsigned short* __restrict__ A,
    const unsigned short* __restrict__ Bw,
    const float* __restrict__ bias,
    _Float16* __restrict__ lamh) {
  __shared__ __attribute__((aligned(16))) unsigned short Alds[128 * 32];  // 8KB
  __shared__ __attribute__((aligned(16))) unsigned short Blds[128 * 32];  // 8KB

  const int t    = threadIdx.x;
  const int wave = t >> 6;
  const int lane = t & 63;
  const int wr   = wave >> 1;     // wave row (0..1), 64 rows each
  const int wc   = wave & 1;      // wave col (0..1), 64 cols each
  const int m0   = blockIdx.x * 128;
  const int n0   = blockIdx.y * 128;

  f32x4 acc[4][4] = {};   // 4x4 fragments of 16x16 per wave -> 64x64

  // Staging: linear16 slot q = issue*256 + t covers LDS bytes [q*16, q*16+16)
  // row = q/4, k-col = (q%4)*8  (row-major [128][32] bf16 tile = 64B rows)
  const int r0 = t >> 2;
  const int c0 = (t & 3) * 8;
  const unsigned short* gA0 = A  + (size_t)(m0 + r0)      * D_ + c0;
  const unsigned short* gA1 = A  + (size_t)(m0 + r0 + 64) * D_ + c0;
  const unsigned short* gB0 = Bw + (size_t)(n0 + r0)      * D_ + c0;
  const unsigned short* gB1 = Bw + (size_t)(n0 + r0 + 64) * D_ + c0;
  // wave-uniform LDS bases (8 shorts = 16B per slot)
  unsigned short* lA0 = Alds + (       wave * 64) * 8;
  unsigned short* lA1 = Alds + (256 +  wave * 64) * 8;
  unsigned short* lB0 = Blds + (       wave * 64) * 8;
  unsigned short* lB1 = Blds + (256 +  wave * 64) * 8;

  // fragment read offsets (elements):
  // A-frag lane l: row = wr*64 + m*16 + (l&15), k = (l>>4)*8 .. +8
  const int aoff = (wr * 64 + (lane & 15)) * 32 + ((lane >> 4) * 8);
  const int boff = (wc * 64 + (lane & 15)) * 32 + ((lane >> 4) * 8);

  for (int kt = 0; kt < D_; kt += 32) {
    gload_lds16(gA0 + kt, lA0);
    gload_lds16(gA1 + kt, lA1);
    gload_lds16(gB0 + kt, lB0);
    gload_lds16(gB1 + kt, lB1);
    __syncthreads();          // drains vmcnt before barrier -> LDS ready
    bf16x8 af[4], bf[4];
#pragma unroll
    for (int m = 0; m < 4; ++m)
      af[m] = *reinterpret_cast<const bf16x8*>(&Alds[aoff + m * 16 * 32]);
#pragma unroll
    for (int n = 0; n < 4; ++n)
      bf[n] = *reinterpret_cast<const bf16x8*>(&Blds[boff + n * 16 * 32]);
#pragma unroll
    for (int m = 0; m < 4; ++m)
#pragma unroll
      for (int n = 0; n < 4; ++n)
        acc[m][n] = __builtin_amdgcn_mfma_f32_16x16x32_bf16(af[m], bf[n], acc[m][n], 0, 0, 0);
    __syncthreads();          // before next-iteration staging overwrites LDS
  }

  // Epilogue: C/D layout col = lane&15, row = (lane>>4)*4 + r  [m89/m91]
  const int erow = m0 + wr * 64 + ((lane >> 4) << 2);
  const int ecol = n0 + wc * 64 + (lane & 15);
#pragma unroll
  for (int n = 0; n < 4; ++n) {
    const int col = ecol + n * 16;
    const float bv = bias[col];
#pragma unroll
    for (int m = 0; m < 4; ++m) {
#pragma unroll
      for (int r = 0; r < 4; ++r) {
        const int row = erow + m * 16 + r;
        const float z = acc[m][n][r] + bv;
        lamh[(size_t)row * D_ + col] = (_Float16)(1.0f / (1.0f + __expf(-z)));
      }
    }
  }
}

// ------------------------------------------------------------- scan pass 1 --
// Per (b, chunk c, 4 d-lanes): local scan with s=0; emit P = prod(lam),
// A = local scan end-state. P/A layout: [c][b*D+d] (transposed for pass2).
__global__ __launch_bounds__(256) void scan_pass1(
    const _Float16* __restrict__ lamh, const float* __restrict__ x,
    float* __restrict__ P, float* __restrict__ Aarr) {
  const int blk = blockIdx.x;
  const int b = blk / CCH, c = blk % CCH;
  const int d4 = threadIdx.x * 4;
  const size_t base = ((size_t)(b * K_ + c * LCH)) * D_ + d4;
  const f16x4*  lp = reinterpret_cast<const f16x4*>(lamh + base);
  const float4* xp = reinterpret_cast<const float4*>(x + base);
  float4 s = {0.f, 0.f, 0.f, 0.f};
  float4 p = {1.f, 1.f, 1.f, 1.f};
#pragma unroll 8
  for (int k = 0; k < LCH; ++k) {
    f16x4  lh = lp[k * (D_ / 4)];
    float4 xv = xp[k * (D_ / 4)];
    float lx = (float)lh.x, ly = (float)lh.y, lz = (float)lh.z, lw = (float)lh.w;
    p.x *= lx; p.y *= ly; p.z *= lz; p.w *= lw;
    s.x = lx * s.x + (1.f - lx) * xv.x;
    s.y = ly * s.y + (1.f - ly) * xv.y;
    s.z = lz * s.z + (1.f - lz) * xv.z;
    s.w = lw * s.w + (1.f - lw) * xv.w;
  }
  const size_t o = (size_t)c * BD_ + b * D_ + d4;
  *reinterpret_cast<float4*>(P + o)    = p;
  *reinterpret_cast<float4*>(Aarr + o) = s;
}

// ------------------------------------------------------------- scan pass 2 --
// Sequential over 256 chunks per (b,d) chain. Transposed layout makes each
// step's loads fully coalesced (16KB line across 4096 threads); batch 8 steps
// of loads to keep 16 loads in flight (latency hiding).
__global__ __launch_bounds__(256) void scan_pass2(
    const float* __restrict__ P, const float* __restrict__ Aarr,
    float* __restrict__ S) {
  const int g = blockIdx.x * 256 + threadIdx.x;  // 0..4095 = b*D+d
  float s = 0.f;
  size_t o = g;
  for (int c0 = 0; c0 < CCH; c0 += 8) {
    float p[8], a[8];
#pragma unroll
    for (int j = 0; j < 8; ++j) {
      p[j] = P[o + (size_t)j * BD_];
      a[j] = Aarr[o + (size_t)j * BD_];
    }
    float sv[8];
#pragma unroll
    for (int j = 0; j < 8; ++j) {
      sv[j] = s;
      s = fmaf(p[j], s, a[j]);
    }
#pragma unroll
    for (int j = 0; j < 8; ++j)
      S[o + (size_t)j * BD_] = sv[j];
    o += (size_t)8 * BD_;
  }
}

// ------------------------------------------------------------- scan pass 3 --
// Replay each chunk with correct incoming state, write outputs.
__global__ __launch_bounds__(256) void scan_pass3(
    const _Float16* __restrict__ lamh, const float* __restrict__ x,
    const float* __restrict__ S, float* __restrict__ out) {
  const int blk = blockIdx.x;
  const int b = blk / CCH, c = blk % CCH;
  const int d4 = threadIdx.x * 4;
  float4 s = *reinterpret_cast<const float4*>(S + (size_t)c * BD_ + b * D_ + d4);
  const size_t base = ((size_t)(b * K_ + c * LCH)) * D_ + d4;
  const f16x4*  lp = reinterpret_cast<const f16x4*>(lamh + base);
  const float4* xp = reinterpret_cast<const float4*>(x + base);
  float4* op = reinterpret_cast<float4*>(out + base);
#pragma unroll 8
  for (int k = 0; k < LCH; ++k) {
    f16x4  lh = lp[k * (D_ / 4)];
    float4 xv = xp[k * (D_ / 4)];
    float lx = (float)lh.x, ly = (float)lh.y, lz = (float)lh.z, lw = (float)lh.w;
    s.x = lx * s.x + (1.f - lx) * xv.x;
    s.y = ly * s.y + (1.f - ly) * xv.y;
    s.z = lz * s.z + (1.f - lz) * xv.z;
    s.w = lw * s.w + (1.f - lw) * xv.w;
    op[k * (D_ / 4)] = s;
  }
}

// ------------------------------------------------------------------ launch --
extern "C" void kernel_launch(void* const* d_in, const int* in_sizes, int n_in,
                              void* d_out, int out_size, void* d_ws, size_t ws_size,
                              hipStream_t stream) {
  const float* x    = (const float*)d_in[0];  // [B,K,D]
  const float* W    = (const float*)d_in[1];  // [D,D]
  const float* bias = (const float*)d_in[2];  // [D]
  float* out = (float*)d_out;

  // workspace carve-up (~146 MiB total)
  char* ws = (char*)d_ws;
  unsigned short* xbf = (unsigned short*)ws;                          // 64 MB
  unsigned short* wbf = (unsigned short*)(ws + (size_t)M_ * D_ * 2);  // 2 MB
  _Float16* lamh = (_Float16*)(ws + (size_t)M_ * D_ * 2 + (size_t)D_ * D_ * 2); // 64 MB
  float* P    = (float*)((char*)lamh + (size_t)M_ * D_ * 2);  // 4 MB
  float* Aarr = P   + (size_t)CCH * BD_;    // 4 MB
  float* S    = Aarr + (size_t)CCH * BD_;   // 4 MB

  cvt_f32_to_bf16<<<2048, 256, 0, stream>>>(x, xbf, M_ * D_ / 4);
  cvt_f32_to_bf16<<<512, 256, 0, stream>>>(W, wbf, D_ * D_ / 4);
  gemm_bias_sigmoid<<<dim3(M_ / 128, D_ / 128), 256, 0, stream>>>(xbf, wbf, bias, lamh);
  scan_pass1<<<B_ * CCH, 256, 0, stream>>>(lamh, x, P, Aarr);
  scan_pass2<<<BD_ / 256, 256, 0, stream>>>(P, Aarr, S);  // 16 blocks
  scan_pass3<<<B_ * CCH, 256, 0, stream>>>(lamh, x, S, out);
}